// Round 7
// baseline (4641.972 us; speedup 1.0000x reference)
//
#include <hip/hip_runtime.h>
#include <math.h>

#define NN 102400
#define FD 128
#define KC 16
#define BG 64
#define NPG 1600
#define NE 3276800
#define NB1 400          // k_s / k_scatter1 edge partitions (== k_s grid)
#define EH (NE / NB1)    // 8192 edges per partition
#define NBK 256          // buckets = graph x quarter
#define NPB 400          // nodes per bucket
#define LDSE 13568       // sort2 LDS edge capacity (12800 avg + 6.8 sigma)
#define S2I 14           // sort2 snapshot slots/thread (14*1024 >= LDSE)
#define ZTOT (16384 + 16384 + 131072 + 8 + 8)   // u32s zeroed by k_s

__device__ __forceinline__ void glob_addf(float* p, float v) {
  unsafeAtomicAdd(p, v);
}
__device__ __forceinline__ unsigned f2bf(float f) {
  unsigned u = __float_as_uint(f);
  u += 0x7FFFu + ((u >> 16) & 1u);
  return (u >> 16) & 0xFFFFu;
}
__device__ __forceinline__ float bf2f(unsigned h) {
  return __uint_as_float(h << 16);
}

// ---------- k_s: softmax^2(x@W+b) + bucket histogram + zero accumulators ----------
__global__ __launch_bounds__(256) void k_s(const float* __restrict__ x,
    const float* __restrict__ W, const float* __restrict__ bb,
    const int* __restrict__ esrc, float* __restrict__ s,
    unsigned* __restrict__ blkhist, unsigned* __restrict__ zbase) {
  __shared__ unsigned h[NBK];
  const int t = threadIdx.x, b = blockIdx.x;
  if (t < NBK) h[t] = 0u;
  for (int i = b * 256 + t; i < ZTOT; i += NB1 * 256) zbase[i] = 0u;
  __syncthreads();
  const int n = b * 256 + t;
  float acc[KC];
#pragma unroll
  for (int k = 0; k < KC; ++k) acc[k] = bb[k];
  const float4* xr = (const float4*)(x + (size_t)n * FD);
#pragma unroll 4
  for (int c = 0; c < FD / 4; ++c) {
    float4 v = xr[c];
    const float* wr = W + c * 4 * KC;   // wave-uniform -> scalar loads
#pragma unroll
    for (int k = 0; k < KC; ++k)
      acc[k] += v.x * wr[k] + v.y * wr[KC + k] + v.z * wr[2 * KC + k] + v.w * wr[3 * KC + k];
  }
#pragma unroll
  for (int r = 0; r < 2; ++r) {
    float m = acc[0];
#pragma unroll
    for (int k = 1; k < KC; ++k) m = fmaxf(m, acc[k]);
    float sum = 0.f;
#pragma unroll
    for (int k = 0; k < KC; ++k) { acc[k] = expf(acc[k] - m); sum += acc[k]; }
    float inv = 1.f / sum;
#pragma unroll
    for (int k = 0; k < KC; ++k) acc[k] *= inv;
  }
  float4* so = (float4*)(s + (size_t)n * KC);
  so[0] = make_float4(acc[0], acc[1], acc[2], acc[3]);
  so[1] = make_float4(acc[4], acc[5], acc[6], acc[7]);
  so[2] = make_float4(acc[8], acc[9], acc[10], acc[11]);
  so[3] = make_float4(acc[12], acc[13], acc[14], acc[15]);
  // bucket histogram over this block's edge partition
  const int e0 = b * EH;
  for (int i = t; i < EH; i += 256) {
    unsigned bk = (unsigned)esrc[e0 + i] / (unsigned)NPB;
    atomicAdd(&h[bk], 1u);              // ds_add no-return
  }
  __syncthreads();
  if (t < NBK) blkhist[t * NB1 + b] = h[t];
}

// ---------- k_scan: single block; blkhist -> absolute scatter offsets + bucket bases ----------
__global__ __launch_bounds__(1024) void k_scan(unsigned* __restrict__ blkhist,
    unsigned* __restrict__ base) {
  __shared__ unsigned csum[1024];
  __shared__ unsigned bincl[NBK];
  __shared__ unsigned bexcl[NBK];
  const int t = threadIdx.x;
  const int bk = t >> 2, q = t & 3;
  const unsigned o0 = (unsigned)bk * NB1 + (unsigned)q * 100u;
  unsigned sum = 0;
  for (int i = 0; i < 100; ++i) sum += blkhist[o0 + i];
  csum[t] = sum;
  __syncthreads();
  unsigned tot = 0, inc = 0;
  if (t < NBK) {
    tot = csum[4 * t] + csum[4 * t + 1] + csum[4 * t + 2] + csum[4 * t + 3];
    inc = tot;
    const int lane = t & 63;
#pragma unroll
    for (int o = 1; o < 64; o <<= 1) {
      unsigned nv = __shfl_up(inc, o, 64);
      if (lane >= o) inc += nv;
    }
    bincl[t] = inc;
  }
  __syncthreads();
  if (t < NBK) {
    unsigned wpre = 0;
    for (int w = 0; w < (t >> 6); ++w) wpre += bincl[w * 64 + 63];
    unsigned e = wpre + inc - tot;
    bexcl[t] = e;
    base[t] = e;
    if (t == NBK - 1) base[NBK] = e + tot;
  }
  __syncthreads();
  unsigned run = bexcl[bk];
  for (int qq = 0; qq < q; ++qq) run += csum[bk * 4 + qq];
  for (int i = 0; i < 100; ++i) {
    unsigned v = blkhist[o0 + i];
    blkhist[o0 + i] = run;
    run += v;
  }
}

// ---------- k_scatter1: edges -> bucket-ordered key16/pay (owner-local runs) ----------
__global__ __launch_bounds__(256) void k_scatter1(const float* __restrict__ ew,
    const int* __restrict__ esrc, const int* __restrict__ edst,
    const unsigned* __restrict__ blkhist, unsigned short* __restrict__ key16,
    unsigned* __restrict__ pay) {
  __shared__ unsigned off[NBK];
  __shared__ unsigned h[NBK];
  const int t = threadIdx.x, b = blockIdx.x;
  if (t < NBK) { off[t] = blkhist[t * NB1 + b]; h[t] = 0u; }
  __syncthreads();
  const int e0 = b * EH;
  for (int i = t; i < EH; i += 256) {
    int e = e0 + i;
    int s0 = esrc[e], d0 = edst[e];
    float w = ew[e];
    unsigned bk = (unsigned)s0 / (unsigned)NPB;
    unsigned g = bk >> 2;
    unsigned r = atomicAdd(&h[bk], 1u);
    unsigned pos = off[bk] + r;
    key16[pos] = (unsigned short)((unsigned)s0 - g * NPG);
    pay[pos] = (((unsigned)d0 - g * NPG) << 16) | f2bf(w);
  }
}

// ---------- k_sort2: per-bucket sort by node; payload reordered IN PLACE via LDS ----------
__global__ __launch_bounds__(1024) void k_sort2(const unsigned short* __restrict__ key16,
    unsigned* pay, const unsigned* __restrict__ base,
    unsigned short* __restrict__ rowp) {
  __shared__ unsigned hist[NPB];
  __shared__ unsigned cur[NPB];
  __shared__ unsigned lpay[LDSE];
  const int t = threadIdx.x, bk = blockIdx.x;
  const int g = bk >> 2, qq = bk & 3;
  const unsigned start = base[bk];
  const unsigned gstart = base[bk & ~3];
  unsigned cnt = base[bk + 1] - start;
  if (cnt > LDSE) cnt = LDSE;           // +6.8 sigma guard
  for (int i = t; i < NPB; i += 1024) hist[i] = 0u;
  __syncthreads();
  unsigned short kk[S2I];
#pragma unroll
  for (int i = 0; i < S2I; ++i) {
    unsigned e = (unsigned)t + (unsigned)(i * 1024);
    kk[i] = 0;
    if (e < cnt) {
      unsigned short key = key16[start + e];
      kk[i] = key;
      lpay[e] = pay[start + e];
      atomicAdd(&hist[key - qq * NPB], 1u);
    }
  }
  __syncthreads();
  unsigned v = 0, inc = 0;
  if (t < NPB) {
    v = hist[t];
    inc = v;
    const int lane = t & 63;
#pragma unroll
    for (int o = 1; o < 64; o <<= 1) {
      unsigned nv = __shfl_up(inc, o, 64);
      if (lane >= o) inc += nv;
    }
    cur[t] = inc;                        // inclusive, temp
  }
  __syncthreads();
  if (t < NPB) {
    unsigned wpre = 0;
    for (int w = 0; w < (t >> 6); ++w) wpre += cur[w * 64 + 63];
    unsigned excl = wpre + inc - v;
    rowp[g * 1601 + qq * NPB + t] = (unsigned short)(start - gstart + excl);
    cur[t] = excl;                       // becomes the scatter cursor
  }
  if (t == 0 && qq == 3)
    rowp[g * 1601 + 1600] = (unsigned short)(base[4 * g + 4] - gstart);
  __syncthreads();
#pragma unroll
  for (int i = 0; i < S2I; ++i) {
    unsigned e = (unsigned)t + (unsigned)(i * 1024);
    if (e < cnt) {
      unsigned r = atomicAdd(&cur[kk[i] - qq * NPB], 1u);
      pay[start + r] = lpay[e];          // in-place: all reads staged above
    }
  }
}

// ---------- k_adj: S^T A S via CSR register segment-sum (R5 shape, chain-2); den folded ----
__global__ __launch_bounds__(256, 6) void k_adj(const float* __restrict__ s,
    const unsigned* __restrict__ pay, const unsigned* __restrict__ base,
    const unsigned short* __restrict__ rowp, float* __restrict__ adj_raw,
    float* __restrict__ den) {
  __shared__ float red[16 * 256];
  __shared__ float scr[4];
  const int t = threadIdx.x;
  const int g = blockIdx.x & 63;            // XCD-spread graphs
  const int oct = blockIdx.x >> 6;          // 0..31
  const int l = t & 15;
  const int slice = oct * 16 + (t >> 4);    // 0..511 per graph
  const int sw = (t >> 4) & 3;              // slice-in-wave
  const unsigned gb = base[g * 4];
  const unsigned* pyg = pay + gb;
  const unsigned short* rp = rowp + g * 1601;
  const float* sG = s + (size_t)g * NPG * KC;
  float acc[16];
#pragma unroll
  for (int k = 0; k < 16; ++k) acc[k] = 0.f;
  float dacc = 0.f;
  for (int i = slice; i < NPG; i += 512) {
    unsigned e0 = rp[i], e1 = rp[i + 1];
    float m = 0.f;
    unsigned e = e0;
    for (; e + 2 <= e1; e += 2) {
      unsigned pk0 = pyg[e], pk1 = pyg[e + 1];
      float sv0 = sG[(pk0 >> 16) * KC + l];
      float sv1 = sG[(pk1 >> 16) * KC + l];
      float t0 = bf2f(pk0 & 0xFFFFu) * sv0;
      float t1 = bf2f(pk1 & 0xFFFFu) * sv1;
      m += t0 + t1;
      dacc = fmaf(t0, sv0, dacc);
      dacc = fmaf(t1, sv1, dacc);
    }
    if (e < e1) {
      unsigned pk0 = pyg[e];
      float sv0 = sG[(pk0 >> 16) * KC + l];
      float t0 = bf2f(pk0 & 0xFFFFu) * sv0;
      m += t0;
      dacc = fmaf(t0, sv0, dacc);
    }
    const float si = sG[i * KC + l];
#pragma unroll
    for (int k = 0; k < 16; ++k)
      acc[k] = fmaf(__shfl(si, sw * 16 + k, 64), m, acc[k]);
  }
  const int sb = t >> 4;
#pragma unroll
  for (int k = 0; k < 16; ++k) red[sb * 256 + k * 16 + l] = acc[k];
  __syncthreads();
  float sum = 0.f;
#pragma unroll
  for (int sl = 0; sl < 16; ++sl) sum += red[sl * 256 + t];
  glob_addf(adj_raw + g * 256 + t, sum);
#pragma unroll
  for (int o = 32; o > 0; o >>= 1) dacc += __shfl_down(dacc, o, 64);
  __syncthreads();
  if ((t & 63) == 0) scr[t >> 6] = dacc;
  __syncthreads();
  if (t == 0) glob_addf(den, scr[0] + scr[1] + scr[2] + scr[3]);
}

// ---------- k_mid: CC = S^T S, out_x = S^T X (R5 shape) ----------
__global__ __launch_bounds__(256, 8) void k_mid(const float* __restrict__ s,
    const float* __restrict__ x, float* __restrict__ cc_raw,
    float* __restrict__ outx_raw) {
  __shared__ float st[100 * KC];
  const int t = threadIdx.x;
  const int g = blockIdx.x >> 4, sub = blockIdx.x & 15;
  const int n0 = g * NPG + sub * 100;
  const int j = t & 127, h = t >> 7;
  const int kc = t >> 4, lc = t & 15;
  for (int u = t; u < 100 * KC; u += 256) st[u] = s[(size_t)n0 * KC + u];
  __syncthreads();
  float accX[8] = {0.f, 0.f, 0.f, 0.f, 0.f, 0.f, 0.f, 0.f};
  float accC = 0.f;
  for (int i = 0; i < 100; ++i) {
    const float xv = x[(size_t)(n0 + i) * FD + j];
    const float* si = st + i * KC;
#pragma unroll
    for (int kk = 0; kk < 8; ++kk) accX[kk] = fmaf(si[h * 8 + kk], xv, accX[kk]);
    accC = fmaf(si[kc], si[lc], accC);
  }
#pragma unroll
  for (int kk = 0; kk < 8; ++kk)
    glob_addf(outx_raw + g * 2048 + (h * 8 + kk) * 128 + j, accX[kk]);
  glob_addf(cc_raw + g * 256 + t, accC);
}

// ---------- k_post: normalize adj, trace, ortho, SELU; last block writes scalars ----------
__device__ __forceinline__ float bred(float v, float* scr) {
#pragma unroll
  for (int o = 32; o > 0; o >>= 1) v += __shfl_down(v, o, 64);
  __syncthreads();
  if ((threadIdx.x & 63) == 0) scr[threadIdx.x >> 6] = v;
  __syncthreads();
  return scr[0] + scr[1] + scr[2] + scr[3];
}

__global__ __launch_bounds__(256) void k_post(const float* __restrict__ adj_raw,
    const float* __restrict__ cc_raw, const float* __restrict__ outx_raw,
    float* __restrict__ out, float* __restrict__ scal, unsigned* __restrict__ done) {
  const int b = blockIdx.x, t = threadIdx.x;
  const int k = t >> 4, l = t & 15;
  __shared__ float m[16 * 17];
  __shared__ float dk[16];
  __shared__ float scr[4];
  const float raw = adj_raw[b * 256 + t];
  const float masked = (k == l) ? 0.f : raw;
  m[k * 17 + l] = masked;
  __syncthreads();
  if (t < 16) {
    float rs = 0.f;
#pragma unroll
    for (int ll = 0; ll < 16; ++ll) rs += m[t * 17 + ll];
    dk[t] = sqrtf(rs) + 1e-12f;
  }
  __syncthreads();
  out[131072 + b * 256 + t] = masked / (dk[k] * dk[l]);
  float tr = bred((k == l) ? raw : 0.f, scr);
  if (t == 0) glob_addf(scal + 1, tr);
  const float c = cc_raw[b * 256 + t];
  float n2 = bred(c * c, scr);
  float diff = c / sqrtf(n2) - ((k == l) ? 0.25f : 0.f);
  float d2 = bred(diff * diff, scr);
  if (t == 0) glob_addf(scal + 2, sqrtf(d2));
  for (int idx = b * 256 + t; idx < 131072; idx += 16384) {
    float xv = outx_raw[idx];
    out[idx] = xv > 0.f ? 1.0507009873554805f * xv
                        : 1.0507009873554805f * 1.6732632423543772f * expm1f(xv);
  }
  __syncthreads();
  if (t == 0) {
    __threadfence();
    unsigned v = __hip_atomic_fetch_add(done, 1u, __ATOMIC_ACQ_REL,
                                        __HIP_MEMORY_SCOPE_AGENT);
    if (v == 63u) {   // last block: all contributions visible
      float den   = __hip_atomic_load(scal + 0, __ATOMIC_RELAXED, __HIP_MEMORY_SCOPE_AGENT);
      float num   = __hip_atomic_load(scal + 1, __ATOMIC_RELAXED, __HIP_MEMORY_SCOPE_AGENT);
      float ortho = __hip_atomic_load(scal + 2, __ATOMIC_RELAXED, __HIP_MEMORY_SCOPE_AGENT);
      out[147456] = -num / den;
      out[147457] = ortho * (1.f / 64.f);
    }
  }
}

// -------------------- launch --------------------
extern "C" void kernel_launch(void* const* d_in, const int* in_sizes, int n_in,
                              void* d_out, int out_size, void* d_ws, size_t ws_size,
                              hipStream_t stream) {
  const float* x  = (const float*)d_in[0];
  const float* W  = (const float*)d_in[1];
  const float* bb = (const float*)d_in[2];
  const float* ew = (const float*)d_in[3];
  const int* esrc = (const int*)d_in[4];
  const int* edst = (const int*)d_in[5];
  float* out = (float*)d_out;
  float* ws = (float*)d_ws;

  float* s_buf   = ws;                                    // 1,638,400 f
  float* adj_raw = s_buf + (size_t)NN * KC;               // 16,384 f   <- zero region start
  float* cc_raw  = adj_raw + 16384;                       // 16,384 f
  float* outx    = cc_raw + 16384;                        // 131,072 f
  float* scal    = outx + 131072;                         // 8 f: [0]=den [1]=num [2]=ortho
  unsigned* done = (unsigned*)(scal + 8);                 // 8 u        <- zero region end
  unsigned* blkhist = done + 8;                           // 256*400 u
  unsigned* base    = blkhist + (size_t)NBK * NB1;        // 260 u (257 used)
  unsigned short* rowp = (unsigned short*)(base + 260);   // 64*1601 u16 (pad to 102,528)
  unsigned short* key16 = rowp + 102528;                  // NE u16
  unsigned* pay = (unsigned*)(key16 + NE);                // NE u32
  // total = 27,485,520 B = 27.5 MB (< 33.69 MB proven available)

  k_s<<<NB1, 256, 0, stream>>>(x, W, bb, esrc, s_buf, blkhist, (unsigned*)adj_raw);
  k_scan<<<1, 1024, 0, stream>>>(blkhist, base);
  k_scatter1<<<NB1, 256, 0, stream>>>(ew, esrc, edst, blkhist, key16, pay);
  k_sort2<<<NBK, 1024, 0, stream>>>(key16, pay, base, rowp);
  k_adj<<<BG * 32, 256, 0, stream>>>(s_buf, pay, base, rowp, adj_raw, scal);
  k_mid<<<BG * 16, 256, 0, stream>>>(s_buf, x, cc_raw, outx);
  k_post<<<64, 256, 0, stream>>>(adj_raw, cc_raw, outx, out, scal, done);
}

// Round 8
// 320.897 us; speedup vs baseline: 14.4656x; 14.4656x over previous
//
#include <hip/hip_runtime.h>
#include <math.h>

#define NN 102400
#define FD 128
#define KC 16
#define BG 64
#define NPG 1600
#define NE 3276800
#define HB 1024          // level-1 hist/scatter blocks
#define EH (NE / HB)     // 3200 edges per block
#define SMAX 56          // ceil(max edges-per-graph / 1024)
#define ZTOT (16384 + 16384 + 131072 + 8 + 8)   // u32s zeroed by k_s

__device__ __forceinline__ void glob_addf(float* p, float v) {
  unsafeAtomicAdd(p, v);
}
__device__ __forceinline__ unsigned f2bf(float f) {
  unsigned u = __float_as_uint(f);
  u += 0x7FFFu + ((u >> 16) & 1u);
  return (u >> 16) & 0xFFFFu;
}
__device__ __forceinline__ float bf2f(unsigned h) {
  return __uint_as_float(h << 16);
}

// -------------------- k_s: softmax^2(x@W+b) + zero accumulators --------------------
__global__ __launch_bounds__(256) void k_s(const float* __restrict__ x,
    const float* __restrict__ W, const float* __restrict__ bb,
    float* __restrict__ s, unsigned* __restrict__ zbase) {
  const int t = threadIdx.x;
  const int n = blockIdx.x * 256 + t;
  for (int i = n; i < ZTOT; i += NN) zbase[i] = 0u;
  float acc[KC];
#pragma unroll
  for (int k = 0; k < KC; ++k) acc[k] = bb[k];
  const float4* xr = (const float4*)(x + (size_t)n * FD);
#pragma unroll 4
  for (int c = 0; c < FD / 4; ++c) {
    float4 v = xr[c];
    const float* wr = W + c * 4 * KC;   // wave-uniform -> scalar loads
#pragma unroll
    for (int k = 0; k < KC; ++k)
      acc[k] += v.x * wr[k] + v.y * wr[KC + k] + v.z * wr[2 * KC + k] + v.w * wr[3 * KC + k];
  }
#pragma unroll
  for (int r = 0; r < 2; ++r) {
    float m = acc[0];
#pragma unroll
    for (int k = 1; k < KC; ++k) m = fmaxf(m, acc[k]);
    float sum = 0.f;
#pragma unroll
    for (int k = 0; k < KC; ++k) { acc[k] = expf(acc[k] - m); sum += acc[k]; }
    float inv = 1.f / sum;
#pragma unroll
    for (int k = 0; k < KC; ++k) acc[k] *= inv;
  }
  float4* so = (float4*)(s + (size_t)n * KC);
  so[0] = make_float4(acc[0], acc[1], acc[2], acc[3]);
  so[1] = make_float4(acc[4], acc[5], acc[6], acc[7]);
  so[2] = make_float4(acc[8], acc[9], acc[10], acc[11]);
  so[3] = make_float4(acc[12], acc[13], acc[14], acc[15]);
}

// -------------------- level-1: per-(graph,block) histogram (R5 exact) --------------------
__global__ __launch_bounds__(256) void k_hist(const int* __restrict__ esrc,
    unsigned* __restrict__ blkhist) {
  __shared__ unsigned h[BG];
  const int t = threadIdx.x, b = blockIdx.x;
  if (t < BG) h[t] = 0u;
  __syncthreads();
  const int e0 = b * EH;
  for (int i = t; i < EH; i += 256) {
    unsigned g = (unsigned)esrc[e0 + i] / (unsigned)NPG;
    atomicAdd(&h[g], 1u);           // ds_add, no-return
  }
  __syncthreads();
  if (t < BG) blkhist[t * HB + b] = h[t];
}

// -------------------- level-1 scan A (R5 exact) --------------------
__global__ __launch_bounds__(1024) void k_scan_a(unsigned* __restrict__ blkhist,
    unsigned* __restrict__ gtot) {
  __shared__ unsigned wsum[16];
  const int t = threadIdx.x, g = blockIdx.x;
  const int lane = t & 63;
  unsigned v = blkhist[g * HB + t];
  unsigned inc = v;
#pragma unroll
  for (int o = 1; o < 64; o <<= 1) {
    unsigned nb = __shfl_up(inc, o, 64);
    if (lane >= o) inc += nb;
  }
  if (lane == 63) wsum[t >> 6] = inc;
  __syncthreads();
  if (t == 0) {
    unsigned run = 0;
#pragma unroll
    for (int i = 0; i < 16; ++i) { unsigned c = wsum[i]; wsum[i] = run; run += c; }
    gtot[g] = run;
  }
  __syncthreads();
  blkhist[g * HB + t] = inc - v + wsum[t >> 6];
}

// -------------------- level-1 scan B (R5 exact) --------------------
__global__ void k_scan_b(const unsigned* __restrict__ gtot, unsigned* __restrict__ gbase) {
  if (threadIdx.x == 0) {
    unsigned run = 0;
    for (int g = 0; g < BG; ++g) { gbase[g] = run; run += gtot[g]; }
    gbase[BG] = run;   // == NE
  }
}

// -------------------- level-1 scatter: sort by graph (R5 exact) --------------------
__global__ __launch_bounds__(256) void k_scatter1(const float* __restrict__ ew,
    const int* __restrict__ esrc, const int* __restrict__ edst,
    const unsigned* __restrict__ blkhist, const unsigned* __restrict__ gbase,
    unsigned short* __restrict__ srcperm, unsigned* __restrict__ pay) {
  __shared__ unsigned h[BG];
  __shared__ unsigned off[BG];
  const int t = threadIdx.x, b = blockIdx.x;
  if (t < BG) { h[t] = 0u; off[t] = gbase[t] + blkhist[t * HB + b]; }
  __syncthreads();
  const int e0 = b * EH;
  for (int i = t; i < EH; i += 256) {
    int e = e0 + i;
    int s0 = esrc[e], d0 = edst[e];
    float w = ew[e];
    unsigned g = (unsigned)s0 / (unsigned)NPG;
    unsigned r = atomicAdd(&h[g], 1u);
    unsigned pos = off[g] + r;
    srcperm[pos] = (unsigned short)((unsigned)s0 - g * NPG);
    pay[pos] = (((unsigned)d0 - g * NPG) << 16) | f2bf(w);
  }
}

// -------------------- level-2: per-graph sort by src -> perm + row_ptr (R5 exact) ----
__global__ __launch_bounds__(1024, 4) void k_sort2(unsigned short* srcperm,
    const unsigned* __restrict__ gbase, unsigned short* __restrict__ rowp) {
  __shared__ unsigned hist[NPG];
  __shared__ unsigned cur[NPG];
  const int t = threadIdx.x;
  const int g = blockIdx.x;
  const unsigned gb = gbase[g];
  const unsigned cnt = gbase[g + 1] - gb;   // ~51200, fits u16
  for (int i = t; i < NPG; i += 1024) hist[i] = 0u;
  __syncthreads();
  unsigned short sv[SMAX];                  // register snapshot of src keys
#pragma unroll
  for (int i = 0; i < SMAX; ++i) {
    unsigned e = (unsigned)t + (unsigned)(i * 1024);
    sv[i] = 0;
    if (e < cnt) {
      sv[i] = srcperm[gb + e];
      atomicAdd(&hist[sv[i]], 1u);
    }
  }
  __syncthreads();
  if (t < 64) {                             // wave-0 scan of 1600 counters
    unsigned loc[25];
    unsigned run = 0;
#pragma unroll
    for (int i = 0; i < 25; ++i) { loc[i] = run; run += hist[t * 25 + i]; }
    unsigned inc = run;
#pragma unroll
    for (int o = 1; o < 64; o <<= 1) {
      unsigned nb = __shfl_up(inc, o, 64);
      if (t >= o) inc += nb;
    }
    unsigned excl = inc - run;
#pragma unroll
    for (int i = 0; i < 25; ++i) cur[t * 25 + i] = excl + loc[i];
  }
  __syncthreads();
  for (int i = t; i < NPG; i += 1024) rowp[g * 1601 + i] = (unsigned short)cur[i];
  if (t == 0) rowp[g * 1601 + NPG] = (unsigned short)cnt;
  __syncthreads();
#pragma unroll
  for (int i = 0; i < SMAX; ++i) {          // scatter perm over own-graph region only
    unsigned e = (unsigned)t + (unsigned)(i * 1024);
    if (e < cnt) {
      unsigned r = atomicAdd(&cur[sv[i]], 1u);
      srcperm[gb + r] = (unsigned short)e;
    }
  }
}

// -------------------- k_adj: R5 shape, 4x-unrolled edge loop; den folded ----------
__global__ __launch_bounds__(256, 6) void k_adj(const float* __restrict__ s,
    const unsigned short* __restrict__ perm, const unsigned* __restrict__ pay,
    const unsigned* __restrict__ gbase, const unsigned short* __restrict__ rowp,
    float* __restrict__ adj_raw, float* __restrict__ den) {
  __shared__ float red[16 * 256];
  __shared__ float scr[4];
  const int t = threadIdx.x;
  const int g = blockIdx.x & 63;            // XCD-spread graphs
  const int oct = blockIdx.x >> 6;          // 0..31
  const int l = t & 15;
  const int slice = oct * 16 + (t >> 4);    // 0..511 per graph
  const int sw = (t >> 4) & 3;              // slice-in-wave
  const unsigned gb = gbase[g];
  const unsigned short* pg = perm + gb;
  const unsigned* pyg = pay + gb;
  const unsigned short* rp = rowp + g * 1601;
  const float* sG = s + (size_t)g * NPG * KC;
  float acc[16];
#pragma unroll
  for (int k = 0; k < 16; ++k) acc[k] = 0.f;
  float dacc = 0.f;
  for (int i = slice; i < NPG; i += 512) {
    unsigned e0 = rp[i], e1 = rp[i + 1];
    float m = 0.f;
    unsigned e = e0;
    for (; e + 4 <= e1; e += 4) {           // 4 independent chains in flight
      unsigned pi0 = pg[e], pi1 = pg[e + 1], pi2 = pg[e + 2], pi3 = pg[e + 3];
      unsigned pk0 = pyg[pi0], pk1 = pyg[pi1], pk2 = pyg[pi2], pk3 = pyg[pi3];
      float sv0 = sG[(pk0 >> 16) * KC + l];
      float sv1 = sG[(pk1 >> 16) * KC + l];
      float sv2 = sG[(pk2 >> 16) * KC + l];
      float sv3 = sG[(pk3 >> 16) * KC + l];
      float t0 = bf2f(pk0 & 0xFFFFu) * sv0;
      float t1 = bf2f(pk1 & 0xFFFFu) * sv1;
      float t2 = bf2f(pk2 & 0xFFFFu) * sv2;
      float t3 = bf2f(pk3 & 0xFFFFu) * sv3;
      m += (t0 + t1) + (t2 + t3);
      dacc = fmaf(t0, sv0, dacc);
      dacc = fmaf(t1, sv1, dacc);
      dacc = fmaf(t2, sv2, dacc);
      dacc = fmaf(t3, sv3, dacc);
    }
    for (; e < e1; ++e) {
      unsigned pk0 = pyg[pg[e]];
      float sv0 = sG[(pk0 >> 16) * KC + l];
      float t0 = bf2f(pk0 & 0xFFFFu) * sv0;
      m += t0;
      dacc = fmaf(t0, sv0, dacc);
    }
    const float si = sG[i * KC + l];
#pragma unroll
    for (int k = 0; k < 16; ++k)
      acc[k] = fmaf(__shfl(si, sw * 16 + k, 64), m, acc[k]);
  }
  const int sb = t >> 4;
#pragma unroll
  for (int k = 0; k < 16; ++k) red[sb * 256 + k * 16 + l] = acc[k];
  __syncthreads();
  float sum = 0.f;
#pragma unroll
  for (int sl = 0; sl < 16; ++sl) sum += red[sl * 256 + t];
  glob_addf(adj_raw + g * 256 + t, sum);
#pragma unroll
  for (int o = 32; o > 0; o >>= 1) dacc += __shfl_down(dacc, o, 64);
  __syncthreads();
  if ((t & 63) == 0) scr[t >> 6] = dacc;
  __syncthreads();
  if (t == 0) glob_addf(den, scr[0] + scr[1] + scr[2] + scr[3]);
}

// -------------------- k_mid: CC = S^T S, out_x = S^T X (R5 exact) --------------------
__global__ __launch_bounds__(256, 8) void k_mid(const float* __restrict__ s,
    const float* __restrict__ x, float* __restrict__ cc_raw,
    float* __restrict__ outx_raw) {
  __shared__ float st[100 * KC];
  const int t = threadIdx.x;
  const int g = blockIdx.x >> 4, sub = blockIdx.x & 15;
  const int n0 = g * NPG + sub * 100;
  const int j = t & 127, h = t >> 7;
  const int kc = t >> 4, lc = t & 15;
  for (int u = t; u < 100 * KC; u += 256) st[u] = s[(size_t)n0 * KC + u];
  __syncthreads();
  float accX[8] = {0.f, 0.f, 0.f, 0.f, 0.f, 0.f, 0.f, 0.f};
  float accC = 0.f;
  for (int i = 0; i < 100; ++i) {
    const float xv = x[(size_t)(n0 + i) * FD + j];
    const float* si = st + i * KC;
#pragma unroll
    for (int kk = 0; kk < 8; ++kk) accX[kk] = fmaf(si[h * 8 + kk], xv, accX[kk]);
    accC = fmaf(si[kc], si[lc], accC);
  }
#pragma unroll
  for (int kk = 0; kk < 8; ++kk)
    glob_addf(outx_raw + g * 2048 + (h * 8 + kk) * 128 + j, accX[kk]);
  glob_addf(cc_raw + g * 256 + t, accC);
}

// -------------------- k_post: normalize adj, trace, ortho, SELU; scalar epilogue ----
__device__ __forceinline__ float bred(float v, float* scr) {
#pragma unroll
  for (int o = 32; o > 0; o >>= 1) v += __shfl_down(v, o, 64);
  __syncthreads();
  if ((threadIdx.x & 63) == 0) scr[threadIdx.x >> 6] = v;
  __syncthreads();
  return scr[0] + scr[1] + scr[2] + scr[3];
}

__global__ __launch_bounds__(256) void k_post(const float* __restrict__ adj_raw,
    const float* __restrict__ cc_raw, const float* __restrict__ outx_raw,
    float* __restrict__ out, float* __restrict__ scal, unsigned* __restrict__ done) {
  const int b = blockIdx.x, t = threadIdx.x;
  const int k = t >> 4, l = t & 15;
  __shared__ float m[16 * 17];
  __shared__ float dk[16];
  __shared__ float scr[4];
  const float raw = adj_raw[b * 256 + t];
  const float masked = (k == l) ? 0.f : raw;
  m[k * 17 + l] = masked;
  __syncthreads();
  if (t < 16) {
    float rs = 0.f;
#pragma unroll
    for (int ll = 0; ll < 16; ++ll) rs += m[t * 17 + ll];
    dk[t] = sqrtf(rs) + 1e-12f;
  }
  __syncthreads();
  out[131072 + b * 256 + t] = masked / (dk[k] * dk[l]);
  float tr = bred((k == l) ? raw : 0.f, scr);
  if (t == 0) glob_addf(scal + 1, tr);
  const float c = cc_raw[b * 256 + t];
  float n2 = bred(c * c, scr);
  float diff = c / sqrtf(n2) - ((k == l) ? 0.25f : 0.f);
  float d2 = bred(diff * diff, scr);
  if (t == 0) glob_addf(scal + 2, sqrtf(d2));
  for (int idx = b * 256 + t; idx < 131072; idx += 16384) {
    float xv = outx_raw[idx];
    out[idx] = xv > 0.f ? 1.0507009873554805f * xv
                        : 1.0507009873554805f * 1.6732632423543772f * expm1f(xv);
  }
  __syncthreads();
  if (t == 0) {
    __threadfence();
    unsigned v = __hip_atomic_fetch_add(done, 1u, __ATOMIC_ACQ_REL,
                                        __HIP_MEMORY_SCOPE_AGENT);
    if (v == 63u) {   // last block: all contributions visible
      float den   = __hip_atomic_load(scal + 0, __ATOMIC_RELAXED, __HIP_MEMORY_SCOPE_AGENT);
      float num   = __hip_atomic_load(scal + 1, __ATOMIC_RELAXED, __HIP_MEMORY_SCOPE_AGENT);
      float ortho = __hip_atomic_load(scal + 2, __ATOMIC_RELAXED, __HIP_MEMORY_SCOPE_AGENT);
      out[147456] = -num / den;
      out[147457] = ortho * (1.f / 64.f);
    }
  }
}

// -------------------- launch --------------------
extern "C" void kernel_launch(void* const* d_in, const int* in_sizes, int n_in,
                              void* d_out, int out_size, void* d_ws, size_t ws_size,
                              hipStream_t stream) {
  const float* x  = (const float*)d_in[0];
  const float* W  = (const float*)d_in[1];
  const float* bb = (const float*)d_in[2];
  const float* ew = (const float*)d_in[3];
  const int* esrc = (const int*)d_in[4];
  const int* edst = (const int*)d_in[5];
  float* out = (float*)d_out;
  float* ws = (float*)d_ws;

  float* s_buf   = ws;                                    // 1,638,400 f
  float* adj_raw = s_buf + (size_t)NN * KC;               // 16,384 f   <- zero region start
  float* cc_raw  = adj_raw + 16384;                       // 16,384 f
  float* outx    = cc_raw + 16384;                        // 131,072 f
  float* scal    = outx + 131072;                         // 8 f: [0]=den [1]=num [2]=ortho
  unsigned* done = (unsigned*)(scal + 8);                 // 8 u        <- zero region end
  unsigned* blkhist = done + 8;                           // 64*1024 u
  unsigned* gtot    = blkhist + (size_t)BG * HB;          // 64 u
  unsigned* gbase   = gtot + BG;                          // 68 u (65 used)
  unsigned short* rowp = (unsigned short*)(gbase + 68);   // 64*1601 u16
  unsigned short* srcperm = rowp + 64 * 1601;             // NE u16 (src keys, then perm)
  unsigned* pay = (unsigned*)(srcperm + NE);              // NE u32 (dst<<16 | bf16 w)
  // total ~= 27.3 MB (< 33.69 MB proven available)

  k_s<<<NN / 256, 256, 0, stream>>>(x, W, bb, s_buf, (unsigned*)adj_raw);
  k_hist<<<HB, 256, 0, stream>>>(esrc, blkhist);
  k_scan_a<<<BG, 1024, 0, stream>>>(blkhist, gtot);
  k_scan_b<<<1, 64, 0, stream>>>(gtot, gbase);
  k_scatter1<<<HB, 256, 0, stream>>>(ew, esrc, edst, blkhist, gbase, srcperm, pay);
  k_sort2<<<BG, 1024, 0, stream>>>(srcperm, gbase, rowp);
  k_adj<<<BG * 32, 256, 0, stream>>>(s_buf, srcperm, pay, gbase, rowp, adj_raw, scal);
  k_mid<<<BG * 16, 256, 0, stream>>>(s_buf, x, cc_raw, outx);
  k_post<<<64, 256, 0, stream>>>(adj_raw, cc_raw, outx, out, scal, done);
}